// Round 2
// baseline (602.664 us; speedup 1.0000x reference)
//
#include <hip/hip_runtime.h>

typedef _Float16 half8_t __attribute__((ext_vector_type(8)));
typedef float    f32x4_t __attribute__((ext_vector_type(4)));

#define OUT_HALF 1351680   // 4096*330

__device__ __forceinline__ float fast_silu(float x) {
    float e = __builtin_amdgcn_exp2f(x * -1.44269504f);
    return x * __builtin_amdgcn_rcpf(1.0f + e);
}

__device__ __forceinline__ float fast_softplus(float x) {
    float e = __builtin_amdgcn_exp2f(x * 1.44269504f);
    return __builtin_amdgcn_logf(1.0f + e) * 0.69314718f;
}

// ---- prep: x[4096][40] fp32 -> x16[4096][64] f16, col40 = 1.0 (bias lane), 41..63 = 0
__global__ __launch_bounds__(256) void prep_x_kernel(const float* __restrict__ x,
                                                     _Float16* __restrict__ x16) {
    int idx = blockIdx.x * 256 + threadIdx.x;
    if (idx >= 4096 * 64) return;
    int b = idx >> 6, cc = idx & 63;
    float v = (cc < 40) ? x[b * 40 + cc] : (cc == 40 ? 1.0f : 0.0f);
    x16[idx] = (_Float16)v;
}

// ---- fused 3-layer ensemble MLP, one (d,e) per block, 1024 batch rows per block
__global__ __launch_bounds__(256, 4) void mlp_kernel(
    const _Float16* __restrict__ x16,
    const float* __restrict__ W1, const float* __restrict__ b1,
    const float* __restrict__ W2, const float* __restrict__ b2,
    const float* __restrict__ W3, const float* __restrict__ b3,
    float* __restrict__ mean_t, float* __restrict__ logvar_t)
{
    __shared__ _Float16 w2s[128 * 136];   // rows padded 128->136 halves
    __shared__ float    b2s[128];

    const int bid   = blockIdx.x;
    const int de    = bid >> 2;
    const int chunk = bid & 3;
    const int tid   = threadIdx.x;
    const int wave  = tid >> 6;
    const int lane  = tid & 63;
    const int c     = lane & 15;   // MFMA: A.m / B.n / C.col
    const int q     = lane >> 4;   // MFMA quad

    // ---- stage W2 (fp32 global -> f16 LDS) with sigma-permutation baked in:
    // w2s[g][32*kf + 8*q + j] = W2[g][32*kf + 16*(j>>2) + 4*q + (j&3)]
    {
        const float* W2g = W2 + (size_t)de * 16384;
        for (int i = tid; i < 2048; i += 256) {
            int g  = i >> 4;
            int kf = (i >> 2) & 3;
            int qq = i & 3;
            f32x4_t a = *(const f32x4_t*)&W2g[g * 128 + kf * 32 + qq * 4];
            f32x4_t bb = *(const f32x4_t*)&W2g[g * 128 + kf * 32 + 16 + qq * 4];
            union { _Float16 hh[8]; half8_t v; } u;
            u.hh[0] = (_Float16)a[0]; u.hh[1] = (_Float16)a[1];
            u.hh[2] = (_Float16)a[2]; u.hh[3] = (_Float16)a[3];
            u.hh[4] = (_Float16)bb[0]; u.hh[5] = (_Float16)bb[1];
            u.hh[6] = (_Float16)bb[2]; u.hh[7] = (_Float16)bb[3];
            *(half8_t*)&w2s[g * 136 + kf * 32 + qq * 8] = u.v;
        }
        if (tid < 128) b2s[tid] = b2[de * 128 + tid];
    }
    __syncthreads();

    // ---- hoist W1 fragments (natural k order; b1 folded via x col 40)
    const float* W1g = W1 + (size_t)de * (128 * 40);
    const float* b1g = b1 + (size_t)de * 128;
    half8_t w1frag[8][2];
    #pragma unroll
    for (int ht = 0; ht < 8; ht++) {
        const int h = ht * 16 + c;
        {   // kf = 0: cols q*8 .. q*8+7 (< 32)
            f32x4_t a = *(const f32x4_t*)&W1g[h * 40 + q * 8];
            f32x4_t bb = *(const f32x4_t*)&W1g[h * 40 + q * 8 + 4];
            union { _Float16 hh[8]; half8_t v; } u;
            #pragma unroll
            for (int r = 0; r < 4; r++) { u.hh[r] = (_Float16)a[r]; u.hh[4 + r] = (_Float16)bb[r]; }
            w1frag[ht][0] = u.v;
        }
        {   // kf = 1: cols 32+q*8 .. +7 ; col40 = b1, >40 = 0
            union { _Float16 hh[8]; half8_t v; } u;
            #pragma unroll
            for (int r = 0; r < 8; r++) u.hh[r] = (_Float16)0.0f;
            if (q == 0) {
                f32x4_t a = *(const f32x4_t*)&W1g[h * 40 + 32];
                f32x4_t bb = *(const f32x4_t*)&W1g[h * 40 + 36];
                #pragma unroll
                for (int r = 0; r < 4; r++) { u.hh[r] = (_Float16)a[r]; u.hh[4 + r] = (_Float16)bb[r]; }
            } else if (q == 1) {
                u.hh[0] = (_Float16)b1g[h];
            }
            w1frag[ht][1] = u.v;
        }
    }

    // ---- hoist W3 as layer-3 MFMA A-fragments (sigma-permuted); rows >=2 zero
    const float* W3g = W3 + (size_t)de * 256;
    half8_t w3frag[4];
    #pragma unroll
    for (int kf = 0; kf < 4; kf++) {
        union { _Float16 hh[8]; half8_t v; } u;
        #pragma unroll
        for (int r = 0; r < 8; r++) u.hh[r] = (_Float16)0.0f;
        if (c < 2) {
            f32x4_t a = *(const f32x4_t*)&W3g[c * 128 + kf * 32 + q * 4];
            f32x4_t bb = *(const f32x4_t*)&W3g[c * 128 + kf * 32 + 16 + q * 4];
            #pragma unroll
            for (int r = 0; r < 4; r++) { u.hh[r] = (_Float16)a[r]; u.hh[4 + r] = (_Float16)bb[r]; }
        }
        w3frag[kf] = u.v;
    }

    const float b3m = b3[de * 2 + 0];
    const float b3l = b3[de * 2 + 1];
    const f32x4_t zero4 = {0.f, 0.f, 0.f, 0.f};
    f32x4_t c3init = zero4;
    if (q == 0) { c3init[0] = b3m; c3init[1] = b3l; }

    #pragma unroll 1
    for (int it = 0; it < 8; it++) {
        const int b0 = chunk * 1024 + it * 128 + wave * 32;

        // x fragments (B operand), direct from L2-resident x16
        half8_t xf[2][2];
        #pragma unroll
        for (int nt = 0; nt < 2; nt++)
            #pragma unroll
            for (int kf = 0; kf < 2; kf++)
                xf[nt][kf] = *(const half8_t*)&x16[(b0 + nt * 16 + c) * 64 + kf * 32 + q * 8];

        // ---- layer 1: D1[h][b] = W1 . xT  (bias via k=40)
        f32x4_t acc1[8][2];
        #pragma unroll
        for (int ht = 0; ht < 8; ht++)
            #pragma unroll
            for (int nt = 0; nt < 2; nt++) {
                f32x4_t a = __builtin_amdgcn_mfma_f32_16x16x32_f16(w1frag[ht][0], xf[nt][0], zero4, 0, 0, 0);
                acc1[ht][nt] = __builtin_amdgcn_mfma_f32_16x16x32_f16(w1frag[ht][1], xf[nt][1], a, 0, 0, 0);
            }

        // silu + pack -> P (these ARE layer-2 B-fragment halves under sigma)
        unsigned P[8][2][2];
        #pragma unroll
        for (int ht = 0; ht < 8; ht++)
            #pragma unroll
            for (int nt = 0; nt < 2; nt++)
                #pragma unroll
                for (int p = 0; p < 2; p++) {
                    float v0 = fast_silu(acc1[ht][nt][2 * p + 0]);
                    float v1 = fast_silu(acc1[ht][nt][2 * p + 1]);
                    P[ht][nt][p] = __builtin_bit_cast(unsigned, __builtin_amdgcn_cvt_pkrtz(v0, v1));
                }

        // ---- layer 2: D2[g][b] = W2 . h1 + b2 (bias via C init)
        f32x4_t acc2[8][2];
        #pragma unroll
        for (int mt = 0; mt < 8; mt++) {
            f32x4_t binit = *(const f32x4_t*)&b2s[mt * 16 + q * 4];
            acc2[mt][0] = binit;
            acc2[mt][1] = binit;
        }
        #pragma unroll
        for (int kf = 0; kf < 4; kf++) {
            half8_t af[8];
            #pragma unroll
            for (int mt = 0; mt < 8; mt++)
                af[mt] = *(const half8_t*)&w2s[(mt * 16 + c) * 136 + kf * 32 + q * 8];
            #pragma unroll
            for (int nt = 0; nt < 2; nt++) {
                union { unsigned u[4]; half8_t h; } bu;
                bu.u[0] = P[2 * kf][nt][0];
                bu.u[1] = P[2 * kf][nt][1];
                bu.u[2] = P[2 * kf + 1][nt][0];
                bu.u[3] = P[2 * kf + 1][nt][1];
                #pragma unroll
                for (int mt = 0; mt < 8; mt++)
                    acc2[mt][nt] = __builtin_amdgcn_mfma_f32_16x16x32_f16(af[mt], bu.h, acc2[mt][nt], 0, 0, 0);
            }
        }

        // silu + pack h2
        unsigned P2[8][2][2];
        #pragma unroll
        for (int mt = 0; mt < 8; mt++)
            #pragma unroll
            for (int nt = 0; nt < 2; nt++)
                #pragma unroll
                for (int p = 0; p < 2; p++) {
                    float v0 = fast_silu(acc2[mt][nt][2 * p + 0]);
                    float v1 = fast_silu(acc2[mt][nt][2 * p + 1]);
                    P2[mt][nt][p] = __builtin_bit_cast(unsigned, __builtin_amdgcn_cvt_pkrtz(v0, v1));
                }

        // ---- layer 3: D3[o][b] via one MFMA chain (rows 0/1 valid, b3 via C init)
        #pragma unroll
        for (int nt = 0; nt < 2; nt++) {
            f32x4_t acc3 = c3init;
            #pragma unroll
            for (int kf = 0; kf < 4; kf++) {
                union { unsigned u[4]; half8_t h; } bu;
                bu.u[0] = P2[2 * kf][nt][0];
                bu.u[1] = P2[2 * kf][nt][1];
                bu.u[2] = P2[2 * kf + 1][nt][0];
                bu.u[3] = P2[2 * kf + 1][nt][1];
                acc3 = __builtin_amdgcn_mfma_f32_16x16x32_f16(w3frag[kf], bu.h, acc3, 0, 0, 0);
            }
            if (q == 0) {
                const int bg = b0 + nt * 16 + c;
                float vm = acc3[0];
                float vl = acc3[1];
                vl = 5.0f - fast_softplus(5.0f - vl);
                vl = -10.0f + fast_softplus(vl + 10.0f);
                // transposed staging: lanes c=0..15 write 64B contiguous
                mean_t[(size_t)de * 4096 + bg]   = vm;
                logvar_t[(size_t)de * 4096 + bg] = vl;
            }
        }
    }
}

// ---- [330][4096] -> [4096][330] transpose for both planes, LDS 32x32 tiles
__global__ __launch_bounds__(256) void transpose_out_kernel(
    const float* __restrict__ mean_t, const float* __restrict__ logvar_t,
    float* __restrict__ out)
{
    __shared__ float tile[32][33];
    const int bg0 = blockIdx.x * 32;
    const int de0 = blockIdx.y * 32;
    const float* src = blockIdx.z ? logvar_t : mean_t;
    float* dst = blockIdx.z ? (out + OUT_HALF) : out;
    const int cidx = threadIdx.x & 31;
    const int r0   = threadIdx.x >> 5;   // 0..7
    #pragma unroll
    for (int k = 0; k < 4; k++) {
        int de_l = r0 + k * 8;
        if (de0 + de_l < 330)
            tile[de_l][cidx] = src[(size_t)(de0 + de_l) * 4096 + bg0 + cidx];
    }
    __syncthreads();
    #pragma unroll
    for (int k = 0; k < 4; k++) {
        int bg_l = r0 + k * 8;
        if (de0 + cidx < 330)
            dst[(size_t)(bg0 + bg_l) * 330 + de0 + cidx] = tile[cidx][bg_l];
    }
}

extern "C" void kernel_launch(void* const* d_in, const int* in_sizes, int n_in,
                              void* d_out, int out_size, void* d_ws, size_t ws_size,
                              hipStream_t stream) {
    (void)in_sizes; (void)n_in; (void)out_size; (void)ws_size;
    const float* x  = (const float*)d_in[0];
    const float* W1 = (const float*)d_in[1];
    const float* b1 = (const float*)d_in[2];
    const float* W2 = (const float*)d_in[3];
    const float* b2 = (const float*)d_in[4];
    const float* W3 = (const float*)d_in[5];
    const float* b3 = (const float*)d_in[6];
    float* out = (float*)d_out;

    _Float16* x16   = (_Float16*)d_ws;                         // 512 KB
    float* mean_t   = (float*)((char*)d_ws + 524288);          // 330*4096 f32 = 5.4 MB
    float* logvar_t = mean_t + 330 * 4096;                     // 5.4 MB

    hipLaunchKernelGGL(prep_x_kernel, dim3(1024), dim3(256), 0, stream, x, x16);
    hipLaunchKernelGGL(mlp_kernel, dim3(1320), dim3(256), 0, stream,
                       x16, W1, b1, W2, b2, W3, b3, mean_t, logvar_t);
    hipLaunchKernelGGL(transpose_out_kernel, dim3(128, 11, 2), dim3(256), 0, stream,
                       mean_t, logvar_t, out);
}

// Round 3
// 359.135 us; speedup vs baseline: 1.6781x; 1.6781x over previous
//
#include <hip/hip_runtime.h>

typedef _Float16 half8_t __attribute__((ext_vector_type(8)));
typedef float    f32x4_t __attribute__((ext_vector_type(4)));

#define OUT_HALF 1351680   // 4096*330
#define NDE 330

// ws layout (bytes)
#define OFF_X16    0u
#define OFF_MEANT  524288u
#define OFF_LOGVT  5931008u
#define OFF_W1H    11337728u   // 330*8192 halves  (W1 frags, b1 folded)
#define OFF_W3H    16744448u   // 330*2048 halves  (W3 frags)
#define OFF_W2H    18096128u   // 330*16384 halves (W2 sigma-permuted)
#define WS_PACKED_BYTES 28909568u

__device__ __forceinline__ float fast_silu(float x) {
    float e = __builtin_amdgcn_exp2f(x * -1.44269504f);
    return x * __builtin_amdgcn_rcpf(1.0f + e);
}

__device__ __forceinline__ float fast_softplus(float x) {
    float e = __builtin_amdgcn_exp2f(x * 1.44269504f);
    return __builtin_amdgcn_logf(1.0f + e) * 0.69314718f;
}

// ---- x prep only (fallback path)
__global__ __launch_bounds__(256) void prep_x_kernel(const float* __restrict__ x,
                                                     _Float16* __restrict__ x16) {
    int idx = blockIdx.x * 256 + threadIdx.x;
    if (idx >= 4096 * 64) return;
    int b = idx >> 6, cc = idx & 63;
    float v = (cc < 40) ? x[b * 40 + cc] : (cc == 40 ? 1.0f : 0.0f);
    x16[idx] = (_Float16)v;
}

// ---- combined prep: x16 + W1/W3 fragment pack + W2 sigma pack (packed path)
// blocks [0,1024): x16 ; [1024,1354): w13 per-de ; [1354,3994): w2 pack
__global__ __launch_bounds__(256) void prep_all_kernel(
    const float* __restrict__ x,
    const float* __restrict__ W1, const float* __restrict__ b1,
    const float* __restrict__ W2, const float* __restrict__ W3,
    _Float16* __restrict__ x16, _Float16* __restrict__ w1h,
    _Float16* __restrict__ w2h, _Float16* __restrict__ w3h)
{
    const int blk = blockIdx.x;
    const int tid = threadIdx.x;
    if (blk < 1024) {
        int idx = blk * 256 + tid;
        int b = idx >> 6, cc = idx & 63;
        float v = (cc < 40) ? x[b * 40 + cc] : (cc == 40 ? 1.0f : 0.0f);
        x16[idx] = (_Float16)v;
        return;
    }
    if (blk < 1024 + NDE) {
        const int de = blk - 1024;
        const float* W1g = W1 + (size_t)de * (128 * 40);
        const float* b1g = b1 + (size_t)de * 128;
        const float* W3g = W3 + (size_t)de * 256;
        // W1 fragment slots: 1024 slots of 8 halves
        for (int s = tid; s < 1024; s += 256) {
            int ht = s >> 7, rem = s & 127, kf = rem >> 6, lane = rem & 63;
            int c = lane & 15, q = lane >> 4, h = ht * 16 + c;
            union { _Float16 hh[8]; half8_t v; } u;
            if (kf == 0) {
                #pragma unroll
                for (int r = 0; r < 8; r++) u.hh[r] = (_Float16)W1g[h * 40 + q * 8 + r];
            } else {
                #pragma unroll
                for (int r = 0; r < 8; r++) u.hh[r] = (_Float16)0.0f;
                if (q == 0) {
                    #pragma unroll
                    for (int r = 0; r < 8; r++) u.hh[r] = (_Float16)W1g[h * 40 + 32 + r];
                } else if (q == 1) {
                    u.hh[0] = (_Float16)b1g[h];
                }
            }
            *(half8_t*)&w1h[(size_t)de * 8192 + (ht * 2 + kf) * 512 + lane * 8] = u.v;
        }
        // W3 fragment slots: 256 slots of 8 halves
        if (tid < 256) {
            int s = tid;
            int kf = s >> 6, lane = s & 63, c = lane & 15, q = lane >> 4;
            union { _Float16 hh[8]; half8_t v; } u;
            #pragma unroll
            for (int r = 0; r < 8; r++) u.hh[r] = (_Float16)0.0f;
            if (c < 2) {
                #pragma unroll
                for (int r = 0; r < 4; r++) {
                    u.hh[r]     = (_Float16)W3g[c * 128 + kf * 32 + q * 4 + r];
                    u.hh[4 + r] = (_Float16)W3g[c * 128 + kf * 32 + 16 + q * 4 + r];
                }
            }
            *(half8_t*)&w3h[(size_t)de * 2048 + kf * 512 + lane * 8] = u.v;
        }
        return;
    }
    // W2 pack: flat f in [0, 330*2048), 8 halves per thread
    int f = (blk - 1024 - NDE) * 256 + tid;
    if (f >= NDE * 2048) return;
    int de = f >> 11, i = f & 2047;
    int g = i >> 4, kf = (i >> 2) & 3, qq = i & 3;
    const float* W2g = W2 + (size_t)de * 16384;
    f32x4_t a  = *(const f32x4_t*)&W2g[g * 128 + kf * 32 + qq * 4];
    f32x4_t bb = *(const f32x4_t*)&W2g[g * 128 + kf * 32 + 16 + qq * 4];
    union { _Float16 hh[8]; half8_t v; } u;
    #pragma unroll
    for (int r = 0; r < 4; r++) { u.hh[r] = (_Float16)a[r]; u.hh[4 + r] = (_Float16)bb[r]; }
    *(half8_t*)&w2h[(size_t)de * 16384 + g * 128 + kf * 32 + qq * 8] = u.v;
}

// ---- fused 3-layer ensemble MLP, one (d,e) per block, 1024 batch rows per block
template <bool PACKED>
__global__ __launch_bounds__(256, 2) void mlp_kernel(
    const _Float16* __restrict__ x16,
    const float* __restrict__ W1, const float* __restrict__ b1,
    const float* __restrict__ W2, const float* __restrict__ b2,
    const float* __restrict__ W3, const float* __restrict__ b3,
    const _Float16* __restrict__ w1h, const _Float16* __restrict__ w2h,
    const _Float16* __restrict__ w3h,
    float* __restrict__ mean_t, float* __restrict__ logvar_t)
{
    __shared__ _Float16 w2s[128 * 136];   // rows padded 128->136 halves
    __shared__ float    b2s[128];

    const int bid   = blockIdx.x;
    const int de    = bid >> 2;
    const int chunk = bid & 3;
    const int tid   = threadIdx.x;
    const int wave  = tid >> 6;
    const int lane  = tid & 63;
    const int c     = lane & 15;   // MFMA: A.m / B.n / C.col
    const int q     = lane >> 4;   // MFMA quad

    // ---- stage W2 into LDS (sigma-permutation: baked by prep, or applied here)
    if constexpr (PACKED) {
        const _Float16* W2g = w2h + (size_t)de * 16384;
        for (int i = tid; i < 2048; i += 256) {
            half8_t v = *(const half8_t*)&W2g[i * 8];
            *(half8_t*)&w2s[(i >> 4) * 136 + (i & 15) * 8] = v;
        }
    } else {
        const float* W2g = W2 + (size_t)de * 16384;
        for (int i = tid; i < 2048; i += 256) {
            int g  = i >> 4;
            int kf = (i >> 2) & 3;
            int qq = i & 3;
            f32x4_t a  = *(const f32x4_t*)&W2g[g * 128 + kf * 32 + qq * 4];
            f32x4_t bb = *(const f32x4_t*)&W2g[g * 128 + kf * 32 + 16 + qq * 4];
            union { _Float16 hh[8]; half8_t v; } u;
            #pragma unroll
            for (int r = 0; r < 4; r++) { u.hh[r] = (_Float16)a[r]; u.hh[4 + r] = (_Float16)bb[r]; }
            *(half8_t*)&w2s[g * 136 + kf * 32 + qq * 8] = u.v;
        }
    }
    if (tid < 128) b2s[tid] = b2[de * 128 + tid];
    __syncthreads();

    // ---- W1 fragments (b1 folded at k=40 / via pack)
    half8_t w1frag[8][2];
    if constexpr (PACKED) {
        const _Float16* src = w1h + (size_t)de * 8192 + lane * 8;
        #pragma unroll
        for (int ht = 0; ht < 8; ht++)
            #pragma unroll
            for (int kf = 0; kf < 2; kf++)
                w1frag[ht][kf] = *(const half8_t*)&src[(ht * 2 + kf) * 512];
    } else {
        const float* W1g = W1 + (size_t)de * (128 * 40);
        const float* b1g = b1 + (size_t)de * 128;
        #pragma unroll
        for (int ht = 0; ht < 8; ht++) {
            const int h = ht * 16 + c;
            {
                f32x4_t a  = *(const f32x4_t*)&W1g[h * 40 + q * 8];
                f32x4_t bb = *(const f32x4_t*)&W1g[h * 40 + q * 8 + 4];
                union { _Float16 hh[8]; half8_t v; } u;
                #pragma unroll
                for (int r = 0; r < 4; r++) { u.hh[r] = (_Float16)a[r]; u.hh[4 + r] = (_Float16)bb[r]; }
                w1frag[ht][0] = u.v;
            }
            {
                union { _Float16 hh[8]; half8_t v; } u;
                #pragma unroll
                for (int r = 0; r < 8; r++) u.hh[r] = (_Float16)0.0f;
                if (q == 0) {
                    f32x4_t a  = *(const f32x4_t*)&W1g[h * 40 + 32];
                    f32x4_t bb = *(const f32x4_t*)&W1g[h * 40 + 36];
                    #pragma unroll
                    for (int r = 0; r < 4; r++) { u.hh[r] = (_Float16)a[r]; u.hh[4 + r] = (_Float16)bb[r]; }
                } else if (q == 1) {
                    u.hh[0] = (_Float16)b1g[h];
                }
                w1frag[ht][1] = u.v;
            }
        }
    }

    // ---- W3 fragments (rows >=2 zero)
    half8_t w3frag[4];
    if constexpr (PACKED) {
        const _Float16* src = w3h + (size_t)de * 2048 + lane * 8;
        #pragma unroll
        for (int kf = 0; kf < 4; kf++)
            w3frag[kf] = *(const half8_t*)&src[kf * 512];
    } else {
        const float* W3g = W3 + (size_t)de * 256;
        #pragma unroll
        for (int kf = 0; kf < 4; kf++) {
            union { _Float16 hh[8]; half8_t v; } u;
            #pragma unroll
            for (int r = 0; r < 8; r++) u.hh[r] = (_Float16)0.0f;
            if (c < 2) {
                f32x4_t a  = *(const f32x4_t*)&W3g[c * 128 + kf * 32 + q * 4];
                f32x4_t bb = *(const f32x4_t*)&W3g[c * 128 + kf * 32 + 16 + q * 4];
                #pragma unroll
                for (int r = 0; r < 4; r++) { u.hh[r] = (_Float16)a[r]; u.hh[4 + r] = (_Float16)bb[r]; }
            }
            w3frag[kf] = u.v;
        }
    }

    const float b3m = b3[de * 2 + 0];
    const float b3l = b3[de * 2 + 1];
    const f32x4_t zero4 = {0.f, 0.f, 0.f, 0.f};
    f32x4_t c3init = zero4;
    if (q == 0) { c3init[0] = b3m; c3init[1] = b3l; }

    #pragma unroll 1
    for (int it = 0; it < 8; it++) {
        const int b0 = chunk * 1024 + it * 128 + wave * 32;

        half8_t xf[2][2];
        #pragma unroll
        for (int nt = 0; nt < 2; nt++)
            #pragma unroll
            for (int kf = 0; kf < 2; kf++)
                xf[nt][kf] = *(const half8_t*)&x16[(b0 + nt * 16 + c) * 64 + kf * 32 + q * 8];

        // ---- layer 1
        f32x4_t acc1[8][2];
        #pragma unroll
        for (int ht = 0; ht < 8; ht++)
            #pragma unroll
            for (int nt = 0; nt < 2; nt++) {
                f32x4_t a = __builtin_amdgcn_mfma_f32_16x16x32_f16(w1frag[ht][0], xf[nt][0], zero4, 0, 0, 0);
                acc1[ht][nt] = __builtin_amdgcn_mfma_f32_16x16x32_f16(w1frag[ht][1], xf[nt][1], a, 0, 0, 0);
            }

        unsigned P[8][2][2];
        #pragma unroll
        for (int ht = 0; ht < 8; ht++)
            #pragma unroll
            for (int nt = 0; nt < 2; nt++)
                #pragma unroll
                for (int p = 0; p < 2; p++) {
                    float v0 = fast_silu(acc1[ht][nt][2 * p + 0]);
                    float v1 = fast_silu(acc1[ht][nt][2 * p + 1]);
                    P[ht][nt][p] = __builtin_bit_cast(unsigned, __builtin_amdgcn_cvt_pkrtz(v0, v1));
                }

        // ---- layer 2
        f32x4_t acc2[8][2];
        #pragma unroll
        for (int mt = 0; mt < 8; mt++) {
            f32x4_t binit = *(const f32x4_t*)&b2s[mt * 16 + q * 4];
            acc2[mt][0] = binit;
            acc2[mt][1] = binit;
        }
        #pragma unroll
        for (int kf = 0; kf < 4; kf++) {
            half8_t af[8];
            #pragma unroll
            for (int mt = 0; mt < 8; mt++)
                af[mt] = *(const half8_t*)&w2s[(mt * 16 + c) * 136 + kf * 32 + q * 8];
            #pragma unroll
            for (int nt = 0; nt < 2; nt++) {
                union { unsigned u[4]; half8_t h; } bu;
                bu.u[0] = P[2 * kf][nt][0];
                bu.u[1] = P[2 * kf][nt][1];
                bu.u[2] = P[2 * kf + 1][nt][0];
                bu.u[3] = P[2 * kf + 1][nt][1];
                #pragma unroll
                for (int mt = 0; mt < 8; mt++)
                    acc2[mt][nt] = __builtin_amdgcn_mfma_f32_16x16x32_f16(af[mt], bu.h, acc2[mt][nt], 0, 0, 0);
            }
        }

        unsigned P2[8][2][2];
        #pragma unroll
        for (int mt = 0; mt < 8; mt++)
            #pragma unroll
            for (int nt = 0; nt < 2; nt++)
                #pragma unroll
                for (int p = 0; p < 2; p++) {
                    float v0 = fast_silu(acc2[mt][nt][2 * p + 0]);
                    float v1 = fast_silu(acc2[mt][nt][2 * p + 1]);
                    P2[mt][nt][p] = __builtin_bit_cast(unsigned, __builtin_amdgcn_cvt_pkrtz(v0, v1));
                }

        // ---- layer 3
        #pragma unroll
        for (int nt = 0; nt < 2; nt++) {
            f32x4_t acc3 = c3init;
            #pragma unroll
            for (int kf = 0; kf < 4; kf++) {
                union { unsigned u[4]; half8_t h; } bu;
                bu.u[0] = P2[2 * kf][nt][0];
                bu.u[1] = P2[2 * kf][nt][1];
                bu.u[2] = P2[2 * kf + 1][nt][0];
                bu.u[3] = P2[2 * kf + 1][nt][1];
                acc3 = __builtin_amdgcn_mfma_f32_16x16x32_f16(w3frag[kf], bu.h, acc3, 0, 0, 0);
            }
            if (q == 0) {
                const int bg = b0 + nt * 16 + c;
                float vm = acc3[0];
                float vl = acc3[1];
                vl = 5.0f - fast_softplus(5.0f - vl);
                vl = -10.0f + fast_softplus(vl + 10.0f);
                mean_t[(size_t)de * 4096 + bg]   = vm;
                logvar_t[(size_t)de * 4096 + bg] = vl;
            }
        }
    }
}

// ---- [330][4096] -> [4096][330] transpose for both planes
__global__ __launch_bounds__(256) void transpose_out_kernel(
    const float* __restrict__ mean_t, const float* __restrict__ logvar_t,
    float* __restrict__ out)
{
    __shared__ float tile[32][33];
    const int bg0 = blockIdx.x * 32;
    const int de0 = blockIdx.y * 32;
    const float* src = blockIdx.z ? logvar_t : mean_t;
    float* dst = blockIdx.z ? (out + OUT_HALF) : out;
    const int cidx = threadIdx.x & 31;
    const int r0   = threadIdx.x >> 5;
    #pragma unroll
    for (int k = 0; k < 4; k++) {
        int de_l = r0 + k * 8;
        if (de0 + de_l < NDE)
            tile[de_l][cidx] = src[(size_t)(de0 + de_l) * 4096 + bg0 + cidx];
    }
    __syncthreads();
    #pragma unroll
    for (int k = 0; k < 4; k++) {
        int bg_l = r0 + k * 8;
        if (de0 + cidx < NDE)
            dst[(size_t)(bg0 + bg_l) * 330 + de0 + cidx] = tile[cidx][bg_l];
    }
}

extern "C" void kernel_launch(void* const* d_in, const int* in_sizes, int n_in,
                              void* d_out, int out_size, void* d_ws, size_t ws_size,
                              hipStream_t stream) {
    (void)in_sizes; (void)n_in; (void)out_size;
    const float* x  = (const float*)d_in[0];
    const float* W1 = (const float*)d_in[1];
    const float* b1 = (const float*)d_in[2];
    const float* W2 = (const float*)d_in[3];
    const float* b2 = (const float*)d_in[4];
    const float* W3 = (const float*)d_in[5];
    const float* b3 = (const float*)d_in[6];
    float* out = (float*)d_out;

    char* ws = (char*)d_ws;
    _Float16* x16   = (_Float16*)(ws + OFF_X16);
    float* mean_t   = (float*)(ws + OFF_MEANT);
    float* logvar_t = (float*)(ws + OFF_LOGVT);

    if (ws_size >= WS_PACKED_BYTES) {
        _Float16* w1h = (_Float16*)(ws + OFF_W1H);
        _Float16* w3h = (_Float16*)(ws + OFF_W3H);
        _Float16* w2h = (_Float16*)(ws + OFF_W2H);
        hipLaunchKernelGGL(prep_all_kernel, dim3(1024 + NDE + 2640), dim3(256), 0, stream,
                           x, W1, b1, W2, W3, x16, w1h, w2h, w3h);
        hipLaunchKernelGGL((mlp_kernel<true>), dim3(NDE * 4), dim3(256), 0, stream,
                           x16, W1, b1, W2, b2, W3, b3, w1h, w2h, w3h, mean_t, logvar_t);
    } else {
        hipLaunchKernelGGL(prep_x_kernel, dim3(1024), dim3(256), 0, stream, x, x16);
        hipLaunchKernelGGL((mlp_kernel<false>), dim3(NDE * 4), dim3(256), 0, stream,
                           x16, W1, b1, W2, b2, W3, b3, x16, x16, x16, mean_t, logvar_t);
    }
    hipLaunchKernelGGL(transpose_out_kernel, dim3(128, 11, 2), dim3(256), 0, stream,
                       mean_t, logvar_t, out);
}

// Round 4
// 326.878 us; speedup vs baseline: 1.8437x; 1.0987x over previous
//
#include <hip/hip_runtime.h>

typedef _Float16 half8_t __attribute__((ext_vector_type(8)));
typedef float    f32x4_t __attribute__((ext_vector_type(4)));

#define OUT_HALF 1351680   // 4096*330
#define NDE 330

// ws layout (bytes)
#define OFF_X16    0u
#define OFF_MEANT  524288u
#define OFF_LOGVT  5931008u
#define OFF_W1H    11337728u   // 330*8192 halves  (W1 frags, b1 folded)
#define OFF_W3H    16744448u   // 330*2048 halves  (W3 frags)
#define OFF_W2H    18096128u   // 330*16384 halves (W2 sigma-permuted)
#define WS_PACKED_BYTES 28909568u

__device__ __forceinline__ float fast_silu(float x) {
    float e = __builtin_amdgcn_exp2f(x * -1.44269504f);
    return x * __builtin_amdgcn_rcpf(1.0f + e);
}

__device__ __forceinline__ float fast_softplus(float x) {
    float e = __builtin_amdgcn_exp2f(x * 1.44269504f);
    return __builtin_amdgcn_logf(1.0f + e) * 0.69314718f;
}

// ---- x prep only (fallback path)
__global__ __launch_bounds__(256) void prep_x_kernel(const float* __restrict__ x,
                                                     _Float16* __restrict__ x16) {
    int idx = blockIdx.x * 256 + threadIdx.x;
    if (idx >= 4096 * 64) return;
    int b = idx >> 6, cc = idx & 63;
    float v = (cc < 40) ? x[b * 40 + cc] : (cc == 40 ? 1.0f : 0.0f);
    x16[idx] = (_Float16)v;
}

// ---- combined prep: x16 + W1/W3 fragment pack + W2 sigma pack (packed path)
__global__ __launch_bounds__(256) void prep_all_kernel(
    const float* __restrict__ x,
    const float* __restrict__ W1, const float* __restrict__ b1,
    const float* __restrict__ W2, const float* __restrict__ W3,
    _Float16* __restrict__ x16, _Float16* __restrict__ w1h,
    _Float16* __restrict__ w2h, _Float16* __restrict__ w3h)
{
    const int blk = blockIdx.x;
    const int tid = threadIdx.x;
    if (blk < 1024) {
        int idx = blk * 256 + tid;
        int b = idx >> 6, cc = idx & 63;
        float v = (cc < 40) ? x[b * 40 + cc] : (cc == 40 ? 1.0f : 0.0f);
        x16[idx] = (_Float16)v;
        return;
    }
    if (blk < 1024 + NDE) {
        const int de = blk - 1024;
        const float* W1g = W1 + (size_t)de * (128 * 40);
        const float* b1g = b1 + (size_t)de * 128;
        const float* W3g = W3 + (size_t)de * 256;
        for (int s = tid; s < 1024; s += 256) {
            int ht = s >> 7, rem = s & 127, kf = rem >> 6, lane = rem & 63;
            int c = lane & 15, q = lane >> 4, h = ht * 16 + c;
            union { _Float16 hh[8]; half8_t v; } u;
            if (kf == 0) {
                #pragma unroll
                for (int r = 0; r < 8; r++) u.hh[r] = (_Float16)W1g[h * 40 + q * 8 + r];
            } else {
                #pragma unroll
                for (int r = 0; r < 8; r++) u.hh[r] = (_Float16)0.0f;
                if (q == 0) {
                    #pragma unroll
                    for (int r = 0; r < 8; r++) u.hh[r] = (_Float16)W1g[h * 40 + 32 + r];
                } else if (q == 1) {
                    u.hh[0] = (_Float16)b1g[h];
                }
            }
            *(half8_t*)&w1h[(size_t)de * 8192 + (ht * 2 + kf) * 512 + lane * 8] = u.v;
        }
        if (tid < 256) {
            int kf = tid >> 6, lane = tid & 63, c = lane & 15, q = lane >> 4;
            union { _Float16 hh[8]; half8_t v; } u;
            #pragma unroll
            for (int r = 0; r < 8; r++) u.hh[r] = (_Float16)0.0f;
            if (c < 2) {
                #pragma unroll
                for (int r = 0; r < 4; r++) {
                    u.hh[r]     = (_Float16)W3g[c * 128 + kf * 32 + q * 4 + r];
                    u.hh[4 + r] = (_Float16)W3g[c * 128 + kf * 32 + 16 + q * 4 + r];
                }
            }
            *(half8_t*)&w3h[(size_t)de * 2048 + kf * 512 + lane * 8] = u.v;
        }
        return;
    }
    int f = (blk - 1024 - NDE) * 256 + tid;
    if (f >= NDE * 2048) return;
    int de = f >> 11, i = f & 2047;
    int g = i >> 4, kf = (i >> 2) & 3, qq = i & 3;
    const float* W2g = W2 + (size_t)de * 16384;
    f32x4_t a  = *(const f32x4_t*)&W2g[g * 128 + kf * 32 + qq * 4];
    f32x4_t bb = *(const f32x4_t*)&W2g[g * 128 + kf * 32 + 16 + qq * 4];
    union { _Float16 hh[8]; half8_t v; } u;
    #pragma unroll
    for (int r = 0; r < 4; r++) { u.hh[r] = (_Float16)a[r]; u.hh[4 + r] = (_Float16)bb[r]; }
    *(half8_t*)&w2h[(size_t)de * 16384 + g * 128 + kf * 32 + qq * 8] = u.v;
}

// ---- fused 3-layer ensemble MLP, layers interleaved to minimize live registers
template <bool PACKED>
__global__ __launch_bounds__(256, 2) void mlp_kernel(
    const _Float16* __restrict__ x16,
    const float* __restrict__ W1, const float* __restrict__ b1,
    const float* __restrict__ W2, const float* __restrict__ b2,
    const float* __restrict__ W3, const float* __restrict__ b3,
    const _Float16* __restrict__ w1h, const _Float16* __restrict__ w2h,
    const _Float16* __restrict__ w3h,
    float* __restrict__ mean_t, float* __restrict__ logvar_t)
{
    __shared__ _Float16 w2s[128 * 136];   // rows padded 128->136 halves
    __shared__ _Float16 w3s[2048];        // layer-3 A fragments
    __shared__ float    b2s[128];

    const int bid   = blockIdx.x;
    const int de    = bid >> 2;
    const int chunk = bid & 3;
    const int tid   = threadIdx.x;
    const int wave  = tid >> 6;
    const int lane  = tid & 63;
    const int c     = lane & 15;
    const int q     = lane >> 4;

    // ---- stage W2 + W3 + b2 into LDS
    if constexpr (PACKED) {
        const _Float16* W2g = w2h + (size_t)de * 16384;
        for (int i = tid; i < 2048; i += 256) {
            half8_t v = *(const half8_t*)&W2g[i * 8];
            *(half8_t*)&w2s[(i >> 4) * 136 + (i & 15) * 8] = v;
        }
        *(half8_t*)&w3s[tid * 8] = *(const half8_t*)&w3h[(size_t)de * 2048 + tid * 8];
    } else {
        const float* W2g = W2 + (size_t)de * 16384;
        for (int i = tid; i < 2048; i += 256) {
            int g  = i >> 4;
            int kf = (i >> 2) & 3;
            int qq = i & 3;
            f32x4_t a  = *(const f32x4_t*)&W2g[g * 128 + kf * 32 + qq * 4];
            f32x4_t bb = *(const f32x4_t*)&W2g[g * 128 + kf * 32 + 16 + qq * 4];
            union { _Float16 hh[8]; half8_t v; } u;
            #pragma unroll
            for (int r = 0; r < 4; r++) { u.hh[r] = (_Float16)a[r]; u.hh[4 + r] = (_Float16)bb[r]; }
            *(half8_t*)&w2s[g * 136 + kf * 32 + qq * 8] = u.v;
        }
        const float* W3g = W3 + (size_t)de * 256;
        {
            int kf = tid >> 6, lane2 = tid & 63, c2 = lane2 & 15, q2 = lane2 >> 4;
            union { _Float16 hh[8]; half8_t v; } u;
            #pragma unroll
            for (int r = 0; r < 8; r++) u.hh[r] = (_Float16)0.0f;
            if (c2 < 2) {
                #pragma unroll
                for (int r = 0; r < 4; r++) {
                    u.hh[r]     = (_Float16)W3g[c2 * 128 + kf * 32 + q2 * 4 + r];
                    u.hh[4 + r] = (_Float16)W3g[c2 * 128 + kf * 32 + 16 + q2 * 4 + r];
                }
            }
            *(half8_t*)&w3s[kf * 512 + lane2 * 8] = u.v;
        }
    }
    if (tid < 128) b2s[tid] = b2[de * 128 + tid];
    __syncthreads();

    // ---- W1 fragments in registers (64 VGPRs)
    half8_t w1frag[8][2];
    if constexpr (PACKED) {
        const _Float16* src = w1h + (size_t)de * 8192 + lane * 8;
        #pragma unroll
        for (int ht = 0; ht < 8; ht++)
            #pragma unroll
            for (int kf = 0; kf < 2; kf++)
                w1frag[ht][kf] = *(const half8_t*)&src[(ht * 2 + kf) * 512];
    } else {
        const float* W1g = W1 + (size_t)de * (128 * 40);
        const float* b1g = b1 + (size_t)de * 128;
        #pragma unroll
        for (int ht = 0; ht < 8; ht++) {
            const int h = ht * 16 + c;
            {
                f32x4_t a  = *(const f32x4_t*)&W1g[h * 40 + q * 8];
                f32x4_t bb = *(const f32x4_t*)&W1g[h * 40 + q * 8 + 4];
                union { _Float16 hh[8]; half8_t v; } u;
                #pragma unroll
                for (int r = 0; r < 4; r++) { u.hh[r] = (_Float16)a[r]; u.hh[4 + r] = (_Float16)bb[r]; }
                w1frag[ht][0] = u.v;
            }
            {
                union { _Float16 hh[8]; half8_t v; } u;
                #pragma unroll
                for (int r = 0; r < 8; r++) u.hh[r] = (_Float16)0.0f;
                if (q == 0) {
                    f32x4_t a  = *(const f32x4_t*)&W1g[h * 40 + 32];
                    f32x4_t bb = *(const f32x4_t*)&W1g[h * 40 + 36];
                    #pragma unroll
                    for (int r = 0; r < 4; r++) { u.hh[r] = (_Float16)a[r]; u.hh[4 + r] = (_Float16)bb[r]; }
                } else if (q == 1) {
                    u.hh[0] = (_Float16)b1g[h];
                }
                w1frag[ht][1] = u.v;
            }
        }
    }

    const float b3m = b3[de * 2 + 0];
    const float b3l = b3[de * 2 + 1];
    const f32x4_t zero4 = {0.f, 0.f, 0.f, 0.f};
    f32x4_t c3init = zero4;
    if (q == 0) { c3init[0] = b3m; c3init[1] = b3l; }

    #pragma unroll 1
    for (int it = 0; it < 8; it++) {
        const int b0 = chunk * 1024 + it * 128 + wave * 32;

        half8_t xf[2][2];
        #pragma unroll
        for (int nt = 0; nt < 2; nt++)
            #pragma unroll
            for (int kf = 0; kf < 2; kf++)
                xf[nt][kf] = *(const half8_t*)&x16[(b0 + nt * 16 + c) * 64 + kf * 32 + q * 8];

        // acc2 initialized with b2 (C-layout broadcast from LDS)
        f32x4_t acc2[8][2];
        #pragma unroll
        for (int mt = 0; mt < 8; mt++) {
            f32x4_t binit = *(const f32x4_t*)&b2s[mt * 16 + q * 4];
            acc2[mt][0] = binit;
            acc2[mt][1] = binit;
        }

        // ---- interleaved layer1 -> layer2, one contraction chunk kf at a time
        #pragma unroll
        for (int kf = 0; kf < 4; kf++) {
            unsigned Pl[2][2][2];
            #pragma unroll
            for (int h2 = 0; h2 < 2; h2++) {
                const int ht = kf * 2 + h2;
                #pragma unroll
                for (int nt = 0; nt < 2; nt++) {
                    f32x4_t a = __builtin_amdgcn_mfma_f32_16x16x32_f16(w1frag[ht][0], xf[nt][0], zero4, 0, 0, 0);
                    f32x4_t t = __builtin_amdgcn_mfma_f32_16x16x32_f16(w1frag[ht][1], xf[nt][1], a, 0, 0, 0);
                    Pl[h2][nt][0] = __builtin_bit_cast(unsigned,
                        __builtin_amdgcn_cvt_pkrtz(fast_silu(t[0]), fast_silu(t[1])));
                    Pl[h2][nt][1] = __builtin_bit_cast(unsigned,
                        __builtin_amdgcn_cvt_pkrtz(fast_silu(t[2]), fast_silu(t[3])));
                }
            }
            half8_t af[8];
            #pragma unroll
            for (int mt = 0; mt < 8; mt++)
                af[mt] = *(const half8_t*)&w2s[(mt * 16 + c) * 136 + kf * 32 + q * 8];
            #pragma unroll
            for (int nt = 0; nt < 2; nt++) {
                union { unsigned u[4]; half8_t h; } bu;
                bu.u[0] = Pl[0][nt][0];
                bu.u[1] = Pl[0][nt][1];
                bu.u[2] = Pl[1][nt][0];
                bu.u[3] = Pl[1][nt][1];
                #pragma unroll
                for (int mt = 0; mt < 8; mt++)
                    acc2[mt][nt] = __builtin_amdgcn_mfma_f32_16x16x32_f16(af[mt], bu.h, acc2[mt][nt], 0, 0, 0);
            }
        }

        // ---- interleaved layer2-silu -> layer3
        f32x4_t acc3[2] = {c3init, c3init};
        #pragma unroll
        for (int kf2 = 0; kf2 < 4; kf2++) {
            half8_t w3f = *(const half8_t*)&w3s[kf2 * 512 + lane * 8];
            #pragma unroll
            for (int nt = 0; nt < 2; nt++) {
                union { unsigned u[4]; half8_t h; } bu;
                #pragma unroll
                for (int h2 = 0; h2 < 2; h2++) {
                    const int mt = kf2 * 2 + h2;
                    bu.u[2 * h2 + 0] = __builtin_bit_cast(unsigned,
                        __builtin_amdgcn_cvt_pkrtz(fast_silu(acc2[mt][nt][0]), fast_silu(acc2[mt][nt][1])));
                    bu.u[2 * h2 + 1] = __builtin_bit_cast(unsigned,
                        __builtin_amdgcn_cvt_pkrtz(fast_silu(acc2[mt][nt][2]), fast_silu(acc2[mt][nt][3])));
                }
                acc3[nt] = __builtin_amdgcn_mfma_f32_16x16x32_f16(w3f, bu.h, acc3[nt], 0, 0, 0);
            }
        }

        #pragma unroll
        for (int nt = 0; nt < 2; nt++) {
            if (q == 0) {
                const int bg = b0 + nt * 16 + c;
                float vm = acc3[nt][0];
                float vl = acc3[nt][1];
                vl = 5.0f - fast_softplus(5.0f - vl);
                vl = -10.0f + fast_softplus(vl + 10.0f);
                mean_t[(size_t)de * 4096 + bg]   = vm;
                logvar_t[(size_t)de * 4096 + bg] = vl;
            }
        }
    }
}

// ---- [330][4096] -> [4096][330] transpose for both planes
__global__ __launch_bounds__(256) void transpose_out_kernel(
    const float* __restrict__ mean_t, const float* __restrict__ logvar_t,
    float* __restrict__ out)
{
    __shared__ float tile[32][33];
    const int bg0 = blockIdx.x * 32;
    const int de0 = blockIdx.y * 32;
    const float* src = blockIdx.z ? logvar_t : mean_t;
    float* dst = blockIdx.z ? (out + OUT_HALF) : out;
    const int cidx = threadIdx.x & 31;
    const int r0   = threadIdx.x >> 5;
    #pragma unroll
    for (int k = 0; k < 4; k++) {
        int de_l = r0 + k * 8;
        if (de0 + de_l < NDE)
            tile[de_l][cidx] = src[(size_t)(de0 + de_l) * 4096 + bg0 + cidx];
    }
    __syncthreads();
    #pragma unroll
    for (int k = 0; k < 4; k++) {
        int bg_l = r0 + k * 8;
        if (de0 + cidx < NDE)
            dst[(size_t)(bg0 + bg_l) * 330 + de0 + cidx] = tile[cidx][bg_l];
    }
}

extern "C" void kernel_launch(void* const* d_in, const int* in_sizes, int n_in,
                              void* d_out, int out_size, void* d_ws, size_t ws_size,
                              hipStream_t stream) {
    (void)in_sizes; (void)n_in; (void)out_size;
    const float* x  = (const float*)d_in[0];
    const float* W1 = (const float*)d_in[1];
    const float* b1 = (const float*)d_in[2];
    const float* W2 = (const float*)d_in[3];
    const float* b2 = (const float*)d_in[4];
    const float* W3 = (const float*)d_in[5];
    const float* b3 = (const float*)d_in[6];
    float* out = (float*)d_out;

    char* ws = (char*)d_ws;
    _Float16* x16   = (_Float16*)(ws + OFF_X16);
    float* mean_t   = (float*)(ws + OFF_MEANT);
    float* logvar_t = (float*)(ws + OFF_LOGVT);

    if (ws_size >= WS_PACKED_BYTES) {
        _Float16* w1h = (_Float16*)(ws + OFF_W1H);
        _Float16* w3h = (_Float16*)(ws + OFF_W3H);
        _Float16* w2h = (_Float16*)(ws + OFF_W2H);
        hipLaunchKernelGGL(prep_all_kernel, dim3(1024 + NDE + 2640), dim3(256), 0, stream,
                           x, W1, b1, W2, W3, x16, w1h, w2h, w3h);
        hipLaunchKernelGGL((mlp_kernel<true>), dim3(NDE * 4), dim3(256), 0, stream,
                           x16, W1, b1, W2, b2, W3, b3, w1h, w2h, w3h, mean_t, logvar_t);
    } else {
        hipLaunchKernelGGL(prep_x_kernel, dim3(1024), dim3(256), 0, stream, x, x16);
        hipLaunchKernelGGL((mlp_kernel<false>), dim3(NDE * 4), dim3(256), 0, stream,
                           x16, W1, b1, W2, b2, W3, b3, x16, x16, x16, mean_t, logvar_t);
    }
    hipLaunchKernelGGL(transpose_out_kernel, dim3(128, 11, 2), dim3(256), 0, stream,
                       mean_t, logvar_t, out);
}

// Round 5
// 323.756 us; speedup vs baseline: 1.8615x; 1.0096x over previous
//
#include <hip/hip_runtime.h>

typedef _Float16 half8_t __attribute__((ext_vector_type(8)));
typedef float    f32x4_t __attribute__((ext_vector_type(4)));

#define OUT_HALF 1351680   // 4096*330
#define NDE 330

// ws layout (bytes)
#define OFF_X16    0u
#define OFF_MEANT  524288u
#define OFF_LOGVT  5931008u
#define OFF_W1H    11337728u   // 330*8192 halves  (W1 frags, b1 folded)
#define OFF_W3H    16744448u   // 330*2048 halves  (W3 frags)
#define OFF_W2H    18096128u   // 330*16384 halves (W2 sigma-permuted)
#define WS_PACKED_BYTES 28909568u

__device__ __forceinline__ float fast_silu(float x) {
    float e = __builtin_amdgcn_exp2f(x * -1.44269504f);
    return x * __builtin_amdgcn_rcpf(1.0f + e);
}

__device__ __forceinline__ float fast_softplus(float x) {
    float e = __builtin_amdgcn_exp2f(x * 1.44269504f);
    return __builtin_amdgcn_logf(1.0f + e) * 0.69314718f;
}

// ---- x prep only (fallback path)
__global__ __launch_bounds__(256) void prep_x_kernel(const float* __restrict__ x,
                                                     _Float16* __restrict__ x16) {
    int idx = blockIdx.x * 256 + threadIdx.x;
    if (idx >= 4096 * 64) return;
    int b = idx >> 6, cc = idx & 63;
    float v = (cc < 40) ? x[b * 40 + cc] : (cc == 40 ? 1.0f : 0.0f);
    x16[idx] = (_Float16)v;
}

// ---- combined prep: x16 + W1/W3 fragment pack + W2 sigma pack (packed path)
__global__ __launch_bounds__(256) void prep_all_kernel(
    const float* __restrict__ x,
    const float* __restrict__ W1, const float* __restrict__ b1,
    const float* __restrict__ W2, const float* __restrict__ W3,
    _Float16* __restrict__ x16, _Float16* __restrict__ w1h,
    _Float16* __restrict__ w2h, _Float16* __restrict__ w3h)
{
    const int blk = blockIdx.x;
    const int tid = threadIdx.x;
    if (blk < 1024) {
        int idx = blk * 256 + tid;
        int b = idx >> 6, cc = idx & 63;
        float v = (cc < 40) ? x[b * 40 + cc] : (cc == 40 ? 1.0f : 0.0f);
        x16[idx] = (_Float16)v;
        return;
    }
    if (blk < 1024 + NDE) {
        const int de = blk - 1024;
        const float* W1g = W1 + (size_t)de * (128 * 40);
        const float* b1g = b1 + (size_t)de * 128;
        const float* W3g = W3 + (size_t)de * 256;
        for (int s = tid; s < 1024; s += 256) {
            int ht = s >> 7, rem = s & 127, kf = rem >> 6, lane = rem & 63;
            int c = lane & 15, q = lane >> 4, h = ht * 16 + c;
            union { _Float16 hh[8]; half8_t v; } u;
            if (kf == 0) {
                f32x4_t a  = *(const f32x4_t*)&W1g[h * 40 + q * 8];
                f32x4_t bb = *(const f32x4_t*)&W1g[h * 40 + q * 8 + 4];
                #pragma unroll
                for (int r = 0; r < 4; r++) { u.hh[r] = (_Float16)a[r]; u.hh[4 + r] = (_Float16)bb[r]; }
            } else {
                #pragma unroll
                for (int r = 0; r < 8; r++) u.hh[r] = (_Float16)0.0f;
                if (q == 0) {
                    f32x4_t a  = *(const f32x4_t*)&W1g[h * 40 + 32];
                    f32x4_t bb = *(const f32x4_t*)&W1g[h * 40 + 36];
                    #pragma unroll
                    for (int r = 0; r < 4; r++) { u.hh[r] = (_Float16)a[r]; u.hh[4 + r] = (_Float16)bb[r]; }
                } else if (q == 1) {
                    u.hh[0] = (_Float16)b1g[h];
                }
            }
            *(half8_t*)&w1h[(size_t)de * 8192 + (ht * 2 + kf) * 512 + lane * 8] = u.v;
        }
        if (tid < 256) {
            int kf = tid >> 6, lane = tid & 63, c = lane & 15, q = lane >> 4;
            union { _Float16 hh[8]; half8_t v; } u;
            #pragma unroll
            for (int r = 0; r < 8; r++) u.hh[r] = (_Float16)0.0f;
            if (c < 2) {
                #pragma unroll
                for (int r = 0; r < 4; r++) {
                    u.hh[r]     = (_Float16)W3g[c * 128 + kf * 32 + q * 4 + r];
                    u.hh[4 + r] = (_Float16)W3g[c * 128 + kf * 32 + 16 + q * 4 + r];
                }
            }
            *(half8_t*)&w3h[(size_t)de * 2048 + kf * 512 + lane * 8] = u.v;
        }
        return;
    }
    int f = (blk - 1024 - NDE) * 256 + tid;
    if (f >= NDE * 2048) return;
    int de = f >> 11, i = f & 2047;
    int g = i >> 4, kf = (i >> 2) & 3, qq = i & 3;
    const float* W2g = W2 + (size_t)de * 16384;
    f32x4_t a  = *(const f32x4_t*)&W2g[g * 128 + kf * 32 + qq * 4];
    f32x4_t bb = *(const f32x4_t*)&W2g[g * 128 + kf * 32 + 16 + qq * 4];
    union { _Float16 hh[8]; half8_t v; } u;
    #pragma unroll
    for (int r = 0; r < 4; r++) { u.hh[r] = (_Float16)a[r]; u.hh[4 + r] = (_Float16)bb[r]; }
    *(half8_t*)&w2h[(size_t)de * 16384 + g * 128 + kf * 32 + qq * 8] = u.v;
}

// ---- fused 3-layer ensemble MLP; XCD-grouped: all 4 chunks of one de land on
// the same XCD (bid%8 round-robin) so the 52 KB packed weights are fetched into
// that XCD's L2 once and reused by all 4 chunk-blocks.
template <bool PACKED>
__global__ __launch_bounds__(256, 2) void mlp_kernel(
    const _Float16* __restrict__ x16,
    const float* __restrict__ W1, const float* __restrict__ b1,
    const float* __restrict__ W2, const float* __restrict__ b2,
    const float* __restrict__ W3, const float* __restrict__ b3,
    const _Float16* __restrict__ w1h, const _Float16* __restrict__ w2h,
    const _Float16* __restrict__ w3h,
    float* __restrict__ mean_t, float* __restrict__ logvar_t)
{
    __shared__ _Float16 w2s[128 * 136];   // rows padded 128->136 halves
    __shared__ _Float16 w3s[2048];        // layer-3 A fragments
    __shared__ float    b2s[128];

    const int bid = blockIdx.x;
    // XCD-aware mapping: xcd = bid%8 fixed per de; chunk varies within XCD.
    const int grp   = bid >> 5;
    const int xcd   = bid & 7;
    const int chunk = (bid >> 3) & 3;
    const int de    = grp * 8 + xcd;
    if (de >= NDE) return;   // whole block exits together (no barrier hazard)

    const int tid   = threadIdx.x;
    const int wave  = tid >> 6;
    const int lane  = tid & 63;
    const int c     = lane & 15;
    const int q     = lane >> 4;

    // ---- stage W2 + W3 + b2 into LDS
    if constexpr (PACKED) {
        const _Float16* W2g = w2h + (size_t)de * 16384;
        for (int i = tid; i < 2048; i += 256) {
            half8_t v = *(const half8_t*)&W2g[i * 8];
            *(half8_t*)&w2s[(i >> 4) * 136 + (i & 15) * 8] = v;
        }
        *(half8_t*)&w3s[tid * 8] = *(const half8_t*)&w3h[(size_t)de * 2048 + tid * 8];
    } else {
        const float* W2g = W2 + (size_t)de * 16384;
        for (int i = tid; i < 2048; i += 256) {
            int g  = i >> 4;
            int kf = (i >> 2) & 3;
            int qq = i & 3;
            f32x4_t a  = *(const f32x4_t*)&W2g[g * 128 + kf * 32 + qq * 4];
            f32x4_t bb = *(const f32x4_t*)&W2g[g * 128 + kf * 32 + 16 + qq * 4];
            union { _Float16 hh[8]; half8_t v; } u;
            #pragma unroll
            for (int r = 0; r < 4; r++) { u.hh[r] = (_Float16)a[r]; u.hh[4 + r] = (_Float16)bb[r]; }
            *(half8_t*)&w2s[g * 136 + kf * 32 + qq * 8] = u.v;
        }
        const float* W3g = W3 + (size_t)de * 256;
        {
            int kf = tid >> 6, lane2 = tid & 63, c2 = lane2 & 15, q2 = lane2 >> 4;
            union { _Float16 hh[8]; half8_t v; } u;
            #pragma unroll
            for (int r = 0; r < 8; r++) u.hh[r] = (_Float16)0.0f;
            if (c2 < 2) {
                #pragma unroll
                for (int r = 0; r < 4; r++) {
                    u.hh[r]     = (_Float16)W3g[c2 * 128 + kf * 32 + q2 * 4 + r];
                    u.hh[4 + r] = (_Float16)W3g[c2 * 128 + kf * 32 + 16 + q2 * 4 + r];
                }
            }
            *(half8_t*)&w3s[kf * 512 + lane2 * 8] = u.v;
        }
    }
    if (tid < 128) b2s[tid] = b2[de * 128 + tid];
    __syncthreads();

    // ---- W1 fragments in registers (64 VGPRs)
    half8_t w1frag[8][2];
    if constexpr (PACKED) {
        const _Float16* src = w1h + (size_t)de * 8192 + lane * 8;
        #pragma unroll
        for (int ht = 0; ht < 8; ht++)
            #pragma unroll
            for (int kf = 0; kf < 2; kf++)
                w1frag[ht][kf] = *(const half8_t*)&src[(ht * 2 + kf) * 512];
    } else {
        const float* W1g = W1 + (size_t)de * (128 * 40);
        const float* b1g = b1 + (size_t)de * 128;
        #pragma unroll
        for (int ht = 0; ht < 8; ht++) {
            const int h = ht * 16 + c;
            {
                f32x4_t a  = *(const f32x4_t*)&W1g[h * 40 + q * 8];
                f32x4_t bb = *(const f32x4_t*)&W1g[h * 40 + q * 8 + 4];
                union { _Float16 hh[8]; half8_t v; } u;
                #pragma unroll
                for (int r = 0; r < 4; r++) { u.hh[r] = (_Float16)a[r]; u.hh[4 + r] = (_Float16)bb[r]; }
                w1frag[ht][0] = u.v;
            }
            {
                union { _Float16 hh[8]; half8_t v; } u;
                #pragma unroll
                for (int r = 0; r < 8; r++) u.hh[r] = (_Float16)0.0f;
                if (q == 0) {
                    f32x4_t a  = *(const f32x4_t*)&W1g[h * 40 + 32];
                    f32x4_t bb = *(const f32x4_t*)&W1g[h * 40 + 36];
                    #pragma unroll
                    for (int r = 0; r < 4; r++) { u.hh[r] = (_Float16)a[r]; u.hh[4 + r] = (_Float16)bb[r]; }
                } else if (q == 1) {
                    u.hh[0] = (_Float16)b1g[h];
                }
                w1frag[ht][1] = u.v;
            }
        }
    }

    const float b3m = b3[de * 2 + 0];
    const float b3l = b3[de * 2 + 1];
    const f32x4_t zero4 = {0.f, 0.f, 0.f, 0.f};
    f32x4_t c3init = zero4;
    if (q == 0) { c3init[0] = b3m; c3init[1] = b3l; }

    #pragma unroll 1
    for (int it = 0; it < 8; it++) {
        const int b0 = chunk * 1024 + it * 128 + wave * 32;

        half8_t xf[2][2];
        #pragma unroll
        for (int nt = 0; nt < 2; nt++)
            #pragma unroll
            for (int kf = 0; kf < 2; kf++)
                xf[nt][kf] = *(const half8_t*)&x16[(b0 + nt * 16 + c) * 64 + kf * 32 + q * 8];

        f32x4_t acc2[8][2];
        #pragma unroll
        for (int mt = 0; mt < 8; mt++) {
            f32x4_t binit = *(const f32x4_t*)&b2s[mt * 16 + q * 4];
            acc2[mt][0] = binit;
            acc2[mt][1] = binit;
        }

        // ---- interleaved layer1 -> layer2, one contraction chunk kf at a time
        #pragma unroll
        for (int kf = 0; kf < 4; kf++) {
            unsigned Pl[2][2][2];
            #pragma unroll
            for (int h2 = 0; h2 < 2; h2++) {
                const int ht = kf * 2 + h2;
                #pragma unroll
                for (int nt = 0; nt < 2; nt++) {
                    f32x4_t a = __builtin_amdgcn_mfma_f32_16x16x32_f16(w1frag[ht][0], xf[nt][0], zero4, 0, 0, 0);
                    f32x4_t t = __builtin_amdgcn_mfma_f32_16x16x32_f16(w1frag[ht][1], xf[nt][1], a, 0, 0, 0);
                    Pl[h2][nt][0] = __builtin_bit_cast(unsigned,
                        __builtin_amdgcn_cvt_pkrtz(fast_silu(t[0]), fast_silu(t[1])));
                    Pl[h2][nt][1] = __builtin_bit_cast(unsigned,
                        __builtin_amdgcn_cvt_pkrtz(fast_silu(t[2]), fast_silu(t[3])));
                }
            }
            half8_t af[8];
            #pragma unroll
            for (int mt = 0; mt < 8; mt++)
                af[mt] = *(const half8_t*)&w2s[(mt * 16 + c) * 136 + kf * 32 + q * 8];
            #pragma unroll
            for (int nt = 0; nt < 2; nt++) {
                union { unsigned u[4]; half8_t h; } bu;
                bu.u[0] = Pl[0][nt][0];
                bu.u[1] = Pl[0][nt][1];
                bu.u[2] = Pl[1][nt][0];
                bu.u[3] = Pl[1][nt][1];
                #pragma unroll
                for (int mt = 0; mt < 8; mt++)
                    acc2[mt][nt] = __builtin_amdgcn_mfma_f32_16x16x32_f16(af[mt], bu.h, acc2[mt][nt], 0, 0, 0);
            }
        }

        // ---- interleaved layer2-silu -> layer3
        f32x4_t acc3[2] = {c3init, c3init};
        #pragma unroll
        for (int kf2 = 0; kf2 < 4; kf2++) {
            half8_t w3f = *(const half8_t*)&w3s[kf2 * 512 + lane * 8];
            #pragma unroll
            for (int nt = 0; nt < 2; nt++) {
                union { unsigned u[4]; half8_t h; } bu;
                #pragma unroll
                for (int h2 = 0; h2 < 2; h2++) {
                    const int mt = kf2 * 2 + h2;
                    bu.u[2 * h2 + 0] = __builtin_bit_cast(unsigned,
                        __builtin_amdgcn_cvt_pkrtz(fast_silu(acc2[mt][nt][0]), fast_silu(acc2[mt][nt][1])));
                    bu.u[2 * h2 + 1] = __builtin_bit_cast(unsigned,
                        __builtin_amdgcn_cvt_pkrtz(fast_silu(acc2[mt][nt][2]), fast_silu(acc2[mt][nt][3])));
                }
                acc3[nt] = __builtin_amdgcn_mfma_f32_16x16x32_f16(w3f, bu.h, acc3[nt], 0, 0, 0);
            }
        }

        #pragma unroll
        for (int nt = 0; nt < 2; nt++) {
            if (q == 0) {
                const int bg = b0 + nt * 16 + c;
                float vm = acc3[nt][0];
                float vl = acc3[nt][1];
                vl = 5.0f - fast_softplus(5.0f - vl);
                vl = -10.0f + fast_softplus(vl + 10.0f);
                mean_t[(size_t)de * 4096 + bg]   = vm;
                logvar_t[(size_t)de * 4096 + bg] = vl;
            }
        }
    }
}

// ---- [330][4096] -> [4096][330] transpose for both planes
__global__ __launch_bounds__(256) void transpose_out_kernel(
    const float* __restrict__ mean_t, const float* __restrict__ logvar_t,
    float* __restrict__ out)
{
    __shared__ float tile[32][33];
    const int bg0 = blockIdx.x * 32;
    const int de0 = blockIdx.y * 32;
    const float* src = blockIdx.z ? logvar_t : mean_t;
    float* dst = blockIdx.z ? (out + OUT_HALF) : out;
    const int cidx = threadIdx.x & 31;
    const int r0   = threadIdx.x >> 5;
    #pragma unroll
    for (int k = 0; k < 4; k++) {
        int de_l = r0 + k * 8;
        if (de0 + de_l < NDE)
            tile[de_l][cidx] = src[(size_t)(de0 + de_l) * 4096 + bg0 + cidx];
    }
    __syncthreads();
    #pragma unroll
    for (int k = 0; k < 4; k++) {
        int bg_l = r0 + k * 8;
        if (de0 + cidx < NDE)
            dst[(size_t)(bg0 + bg_l) * 330 + de0 + cidx] = tile[cidx][bg_l];
    }
}

extern "C" void kernel_launch(void* const* d_in, const int* in_sizes, int n_in,
                              void* d_out, int out_size, void* d_ws, size_t ws_size,
                              hipStream_t stream) {
    (void)in_sizes; (void)n_in; (void)out_size;
    const float* x  = (const float*)d_in[0];
    const float* W1 = (const float*)d_in[1];
    const float* b1 = (const float*)d_in[2];
    const float* W2 = (const float*)d_in[3];
    const float* b2 = (const float*)d_in[4];
    const float* W3 = (const float*)d_in[5];
    const float* b3 = (const float*)d_in[6];
    float* out = (float*)d_out;

    char* ws = (char*)d_ws;
    _Float16* x16   = (_Float16*)(ws + OFF_X16);
    float* mean_t   = (float*)(ws + OFF_MEANT);
    float* logvar_t = (float*)(ws + OFF_LOGVT);

    // 42 groups x 32 blocks: de = grp*8 + (bid&7), chunk = (bid>>3)&3
    const int MLP_GRID = 42 * 32;

    if (ws_size >= WS_PACKED_BYTES) {
        _Float16* w1h = (_Float16*)(ws + OFF_W1H);
        _Float16* w3h = (_Float16*)(ws + OFF_W3H);
        _Float16* w2h = (_Float16*)(ws + OFF_W2H);
        hipLaunchKernelGGL(prep_all_kernel, dim3(1024 + NDE + 2640), dim3(256), 0, stream,
                           x, W1, b1, W2, W3, x16, w1h, w2h, w3h);
        hipLaunchKernelGGL((mlp_kernel<true>), dim3(MLP_GRID), dim3(256), 0, stream,
                           x16, W1, b1, W2, b2, W3, b3, w1h, w2h, w3h, mean_t, logvar_t);
    } else {
        hipLaunchKernelGGL(prep_x_kernel, dim3(1024), dim3(256), 0, stream, x, x16);
        hipLaunchKernelGGL((mlp_kernel<false>), dim3(MLP_GRID), dim3(256), 0, stream,
                           x16, W1, b1, W2, b2, W3, b3, x16, x16, x16, mean_t, logvar_t);
    }
    hipLaunchKernelGGL(transpose_out_kernel, dim3(128, 11, 2), dim3(256), 0, stream,
                       mean_t, logvar_t, out);
}